// Round 2
// baseline (1172.757 us; speedup 1.0000x reference)
//
#include <hip/hip_runtime.h>

typedef unsigned short ushort_t;
typedef unsigned int uint_t;

typedef __bf16 bf16x8 __attribute__((ext_vector_type(8)));
typedef float  floatx4 __attribute__((ext_vector_type(4)));

#define AS3 __attribute__((address_space(3)))
#define AS1 __attribute__((address_space(1)))

// ---------------- dims ----------------
#define BATCH 512
#define D_IN  120000
#define N1P   640   // 600 padded to 5*128
#define N2P   640
#define N3P   320
#define N4P   256
#define N5P   256

// ---------------- workspace layout ----------------
// [W1 bf16][W2..W5 f32][y1 f32]  <- zeroed region
// [Xb bf16 (aliased by h1,h2,y3,h3,y4,h4 after gemm1)]
static constexpr long O_W1 = 0;                          // bf16 [640][120000]
static constexpr long SZ_W1 = 640L * 120000 * 2;         // 153,600,000
static constexpr long O_W2 = O_W1 + SZ_W1;               // f32 [640][640]
static constexpr long SZ_W2 = 640L * 640 * 4;
static constexpr long O_W3 = O_W2 + SZ_W2;               // f32 [320][640]
static constexpr long SZ_W3 = 320L * 640 * 4;
static constexpr long O_W4 = O_W3 + SZ_W3;               // f32 [256][320]
static constexpr long SZ_W4 = 256L * 320 * 4;
static constexpr long O_W5 = O_W4 + SZ_W4;               // f32 [256][256]
static constexpr long SZ_W5 = 256L * 256 * 4;
static constexpr long O_Y1 = O_W5 + SZ_W5;               // f32 [512][640] split-K target
static constexpr long SZ_Y1 = 512L * 640 * 4;
static constexpr long ZERO_BYTES = O_Y1 + SZ_Y1;         // 157,958,144 (16-divisible)
static constexpr long O_XB = ZERO_BYTES;                 // bf16 [512][120000]
static constexpr long SZ_XB = 512L * 120000 * 2;         // 122,880,000
// h-buffers alias Xb (Xb is dead once gemm1 completes)
static constexpr long O_H1 = O_XB;                       // f32 [512][640]
static constexpr long O_H2 = O_H1 + 512L * 640 * 4;      // f32 [512][640]
static constexpr long O_Y3 = O_H2 + 512L * 640 * 4;      // f32 [512][320]
static constexpr long O_H3 = O_Y3 + 512L * 320 * 4;      // f32 [512][320]
static constexpr long O_Y4 = O_H3 + 512L * 320 * 4;      // f32 [512][256]
static constexpr long O_H4 = O_Y4 + 512L * 256 * 4;      // f32 [512][256]
// total ws requirement = O_XB + SZ_XB = 280,838,144 bytes

// ---------------- helpers ----------------
__device__ __forceinline__ ushort_t f2bf(float f) {
    union { float f; uint_t u; } x;
    x.f = f;
    uint_t u = x.u;
    return (ushort_t)((u + 0x7FFFu + ((u >> 16) & 1u)) >> 16);  // RNE
}
__device__ __forceinline__ float bf2f(ushort_t h) {
    union { uint_t u; float f; } x;
    x.u = ((uint_t)h) << 16;
    return x.f;
}
__device__ __forceinline__ float silu_f(float z) {
    return z / (1.f + expf(-z));
}
__device__ __forceinline__ void load16_lds(const void* g, void* l) {
    __builtin_amdgcn_global_load_lds((const AS1 char*)g, (AS3 char*)l, 16, 0, 0);
}

// ---------------- zero workspace ----------------
__global__ void zero_f4(float4* __restrict__ p, long n4) {
    long stride = (long)gridDim.x * blockDim.x;
    for (long i = (long)blockIdx.x * blockDim.x + threadIdx.x; i < n4; i += stride)
        p[i] = make_float4(0.f, 0.f, 0.f, 0.f);
}

// ---------------- cast x: fp32 -> bf16, 8 elems/thread ----------------
__global__ void cast_f32_bf16(const float* __restrict__ X, ushort_t* __restrict__ Xb, long n8) {
    long t = (long)blockIdx.x * blockDim.x + threadIdx.x;
    if (t >= n8) return;
    const float4* p = (const float4*)X + 2 * t;
    float4 a = p[0], b = p[1];
    union { ushort_t us[8]; uint4 v; } u;
    u.us[0] = f2bf(a.x); u.us[1] = f2bf(a.y); u.us[2] = f2bf(a.z); u.us[3] = f2bf(a.w);
    u.us[4] = f2bf(b.x); u.us[5] = f2bf(b.y); u.us[6] = f2bf(b.z); u.us[7] = f2bf(b.w);
    ((uint4*)Xb)[t] = u.v;
}

// ---------------- scatter layer-1 fp32 values into dense bf16 W1 (CAS add) ----------------
__global__ void scatter_bf16(const int* __restrict__ idx, const float* __restrict__ vals,
                             int nnz, ushort_t* __restrict__ W, int ldw) {
    int i = blockIdx.x * blockDim.x + threadIdx.x;
    if (i >= nnz) return;
    int r = idx[i];
    int c = idx[nnz + i];
    float v = vals[i];
    size_t e = (size_t)r * ldw + c;
    uint_t* word = (uint_t*)((char*)W + ((e * 2) & ~(size_t)3));
    bool hi = (e & 1);
    uint_t cur = *word, assumed;
    do {
        assumed = cur;
        ushort_t h = hi ? (ushort_t)(assumed >> 16) : (ushort_t)(assumed & 0xFFFFu);
        ushort_t nh = f2bf(bf2f(h) + v);
        uint_t nw = hi ? ((assumed & 0x0000FFFFu) | ((uint_t)nh << 16))
                       : ((assumed & 0xFFFF0000u) | (uint_t)nh);
        cur = atomicCAS(word, assumed, nw);
    } while (cur != assumed);
}

// ---------------- scatter small layers into dense fp32 W ----------------
__global__ void scatter_f32(const int* __restrict__ idx, const float* __restrict__ vals,
                            int nnz, float* __restrict__ W, int ldw) {
    int i = blockIdx.x * blockDim.x + threadIdx.x;
    if (i >= nnz) return;
    atomicAdd(&W[(size_t)idx[i] * ldw + idx[nnz + i]], vals[i]);
}

// ---------------- GEMM1: y1(512x640,f32) += Xb(512x120000,bf16) @ W1^T(640x120000,bf16) ----------------
// grid = (20 tiles = 4m x 5n, 30 k-splits), block = 256
__global__ __launch_bounds__(256) void gemm1(const ushort_t* __restrict__ X,
                                             const ushort_t* __restrict__ W,
                                             float* __restrict__ Y, int kChunk) {
    __shared__ ushort_t sA[128 * 32];
    __shared__ ushort_t sB[128 * 32];

    const int tile = blockIdx.x;
    const int bm = tile / 5, bn = tile % 5;
    const int ks = blockIdx.y * kChunk;
    const int iters = kChunk / 32;  // 125

    const int t = threadIdx.x;
    const int lane = t & 63;
    const int w = t >> 6;
    const int wm = w >> 1, wn = w & 1;

    // staging: chunk c covers row c>>2, k-quad c&3 (8 elems, 16B); lane i of wave w owns
    // chunks w*128+i and w*128+64+i; LDS dest = base + lane*16 matches sA[row*32 + quad*8].
    const int c0 = w * 128 + lane;
    const int c1 = c0 + 64;
    const int rA0 = c0 >> 2, qA0 = c0 & 3;
    const int rA1 = c1 >> 2, qA1 = c1 & 3;

    const ushort_t* pa0 = X + (size_t)(bm * 128 + rA0) * D_IN + ks + qA0 * 8;
    const ushort_t* pa1 = X + (size_t)(bm * 128 + rA1) * D_IN + ks + qA1 * 8;
    const ushort_t* pb0 = W + (size_t)(bn * 128 + rA0) * D_IN + ks + qA0 * 8;
    const ushort_t* pb1 = W + (size_t)(bn * 128 + rA1) * D_IN + ks + qA1 * 8;

    ushort_t* la0 = sA + (size_t)(w * 128) * 8;
    ushort_t* la1 = sA + (size_t)(w * 128 + 64) * 8;
    ushort_t* lb0 = sB + (size_t)(w * 128) * 8;
    ushort_t* lb1 = sB + (size_t)(w * 128 + 64) * 8;

    const int i16 = lane & 15;
    const int qk = lane >> 4;
    const bf16x8* ap[4];
    const bf16x8* bp[4];
#pragma unroll
    for (int mi = 0; mi < 4; mi++)
        ap[mi] = (const bf16x8*)&sA[(size_t)(wm * 64 + mi * 16 + i16) * 32 + qk * 8];
#pragma unroll
    for (int ni = 0; ni < 4; ni++)
        bp[ni] = (const bf16x8*)&sB[(size_t)(wn * 64 + ni * 16 + i16) * 32 + qk * 8];

    floatx4 acc[4][4] = {};

    for (int it = 0; it < iters; ++it) {
        __syncthreads();
        load16_lds(pa0, la0);
        load16_lds(pa1, la1);
        load16_lds(pb0, lb0);
        load16_lds(pb1, lb1);
        pa0 += 32; pa1 += 32; pb0 += 32; pb1 += 32;
        __syncthreads();

        bf16x8 af[4], bfr[4];
#pragma unroll
        for (int mi = 0; mi < 4; mi++) af[mi] = *ap[mi];
#pragma unroll
        for (int ni = 0; ni < 4; ni++) bfr[ni] = *bp[ni];
#pragma unroll
        for (int mi = 0; mi < 4; mi++)
#pragma unroll
            for (int ni = 0; ni < 4; ni++)
                acc[mi][ni] = __builtin_amdgcn_mfma_f32_16x16x32_bf16(af[mi], bfr[ni], acc[mi][ni], 0, 0, 0);
    }

    // epilogue: split-K atomic accumulate (C/D: col = lane&15, row = (lane>>4)*4 + reg)
#pragma unroll
    for (int mi = 0; mi < 4; mi++) {
#pragma unroll
        for (int ni = 0; ni < 4; ni++) {
#pragma unroll
            for (int r = 0; r < 4; r++) {
                int row = bm * 128 + wm * 64 + mi * 16 + qk * 4 + r;
                int col = bn * 128 + wn * 64 + ni * 16 + i16;
                atomicAdd(&Y[(size_t)row * N1P + col], acc[mi][ni][r]);
            }
        }
    }
}

// ---------------- BatchNorm (training, biased var) + SiLU, per-column ----------------
__global__ void bn_silu(const float* __restrict__ Y, int ld, int realN,
                        const float* __restrict__ g, const float* __restrict__ be,
                        float* __restrict__ H) {
    int j = blockIdx.x;
    int t = threadIdx.x;
    if (j >= realN) {
        for (int b = t; b < BATCH; b += 256) H[(size_t)b * ld + j] = 0.f;
        return;
    }
    float v0 = Y[(size_t)t * ld + j];
    float v1 = Y[(size_t)(t + 256) * ld + j];
    __shared__ float rs[256], rss[256];
    rs[t] = v0 + v1;
    rss[t] = v0 * v0 + v1 * v1;
    __syncthreads();
    for (int o = 128; o > 0; o >>= 1) {
        if (t < o) { rs[t] += rs[t + o]; rss[t] += rss[t + o]; }
        __syncthreads();
    }
    float mean = rs[0] * (1.f / 512.f);
    float var  = rss[0] * (1.f / 512.f) - mean * mean;
    float sc = rsqrtf(var + 1e-5f) * g[j];
    float sh = be[j] - mean * sc;
    H[(size_t)t * ld + j]         = silu_f(v0 * sc + sh);
    H[(size_t)(t + 256) * ld + j] = silu_f(v1 * sc + sh);
}

// ---------------- small fp32 GEMM: C(512 x N) = A(512 x K) @ W^T(N x K) ----------------
// tile 64x64, BK=16, block=256; dims padded. ACT: 1=silu. GUARD: 1=store only col<outN.
template <int ACT, int GUARD>
__global__ __launch_bounds__(256) void small_gemm(const float* __restrict__ A, int lda,
                                                  const float* __restrict__ W, int ldw,
                                                  const float* __restrict__ bias, int biasN,
                                                  float* __restrict__ out, int ldo, int outN,
                                                  int K) {
    __shared__ float sA[64][20];
    __shared__ float sB[64][20];
    const int t = threadIdx.x;
    const int m0 = blockIdx.x * 64, n0 = blockIdx.y * 64;
    const int ty = t >> 4, tx = t & 15;
    const int lm = t >> 2, lq = t & 3;
    float acc[4][4] = {};

    for (int kt = 0; kt < K; kt += 16) {
        __syncthreads();
        float4 av = *(const float4*)&A[(size_t)(m0 + lm) * lda + kt + lq * 4];
        float4 wv = *(const float4*)&W[(size_t)(n0 + lm) * ldw + kt + lq * 4];
        sA[lm][lq * 4 + 0] = av.x; sA[lm][lq * 4 + 1] = av.y;
        sA[lm][lq * 4 + 2] = av.z; sA[lm][lq * 4 + 3] = av.w;
        sB[lm][lq * 4 + 0] = wv.x; sB[lm][lq * 4 + 1] = wv.y;
        sB[lm][lq * 4 + 2] = wv.z; sB[lm][lq * 4 + 3] = wv.w;
        __syncthreads();
#pragma unroll
        for (int kg = 0; kg < 4; kg++) {
            float4 a4[4], b4[4];
#pragma unroll
            for (int i = 0; i < 4; i++) a4[i] = *(const float4*)&sA[ty * 4 + i][kg * 4];
#pragma unroll
            for (int j = 0; j < 4; j++) b4[j] = *(const float4*)&sB[tx * 4 + j][kg * 4];
#pragma unroll
            for (int i = 0; i < 4; i++)
#pragma unroll
                for (int j = 0; j < 4; j++)
                    acc[i][j] += a4[i].x * b4[j].x + a4[i].y * b4[j].y +
                                 a4[i].z * b4[j].z + a4[i].w * b4[j].w;
        }
    }

#pragma unroll
    for (int i = 0; i < 4; i++) {
#pragma unroll
        for (int j = 0; j < 4; j++) {
            int row = m0 + ty * 4 + i;
            int col = n0 + tx * 4 + j;
            float v = acc[i][j];
            if (bias != nullptr && col < biasN) v += bias[col];
            if (ACT == 1) v = silu_f(v);
            if (GUARD) {
                if (col < outN) out[(size_t)row * ldo + col] = v;
            } else {
                out[(size_t)row * ldo + col] = v;
            }
        }
    }
}

// ---------------- launch ----------------
extern "C" void kernel_launch(void* const* d_in, const int* in_sizes, int n_in,
                              void* d_out, int out_size, void* d_ws, size_t ws_size,
                              hipStream_t stream) {
    // order: x, idx1, val1, b1, idx2, val2, b2, idx3, val3, b3,
    //        idx4, val4, b4, idx5, val5, b5, g1, be1, g2, be2, g3, be3
    const float* x   = (const float*)d_in[0];
    const int* idx1 = (const int*)d_in[1];  const float* val1 = (const float*)d_in[2];
    const int* idx2 = (const int*)d_in[4];  const float* val2 = (const float*)d_in[5];
    const float* b2 = (const float*)d_in[6];
    const int* idx3 = (const int*)d_in[7];  const float* val3 = (const float*)d_in[8];
    const int* idx4 = (const int*)d_in[10]; const float* val4 = (const float*)d_in[11];
    const int* idx5 = (const int*)d_in[13]; const float* val5 = (const float*)d_in[14];
    const float* b5 = (const float*)d_in[15];
    const float* g1 = (const float*)d_in[16]; const float* be1 = (const float*)d_in[17];
    const float* g2 = (const float*)d_in[18]; const float* be2 = (const float*)d_in[19];
    const float* g3 = (const float*)d_in[20]; const float* be3 = (const float*)d_in[21];

    const int nnz1 = in_sizes[1] / 2;
    const int nnz2 = in_sizes[4] / 2;
    const int nnz3 = in_sizes[7] / 2;
    const int nnz4 = in_sizes[10] / 2;
    const int nnz5 = in_sizes[13] / 2;

    char* ws = (char*)d_ws;
    ushort_t* W1 = (ushort_t*)(ws + O_W1);
    float* W2 = (float*)(ws + O_W2);
    float* W3 = (float*)(ws + O_W3);
    float* W4 = (float*)(ws + O_W4);
    float* W5 = (float*)(ws + O_W5);
    float* y1 = (float*)(ws + O_Y1);
    ushort_t* Xb = (ushort_t*)(ws + O_XB);
    float* h1 = (float*)(ws + O_H1);
    float* h2 = (float*)(ws + O_H2);
    float* y3 = (float*)(ws + O_Y3);
    float* h3 = (float*)(ws + O_H3);
    float* y4 = (float*)(ws + O_Y4);
    float* h4 = (float*)(ws + O_H4);

    // 1) zero W1..W5 + y1
    zero_f4<<<dim3(2048), dim3(256), 0, stream>>>((float4*)ws, ZERO_BYTES / 16);

    // 2) cast x -> bf16 (8 elems/thread)
    {
        long n8 = (long)BATCH * D_IN / 8;  // 7,680,000
        cast_f32_bf16<<<dim3((unsigned)((n8 + 255) / 256)), dim3(256), 0, stream>>>(x, Xb, n8);
    }

    // 3) densify weights
    scatter_bf16<<<dim3((nnz1 + 255) / 256), dim3(256), 0, stream>>>(idx1, val1, nnz1, W1, D_IN);
    scatter_f32<<<dim3((nnz2 + 255) / 256), dim3(256), 0, stream>>>(idx2, val2, nnz2, W2, 640);
    scatter_f32<<<dim3((nnz3 + 255) / 256), dim3(256), 0, stream>>>(idx3, val3, nnz3, W3, 640);
    scatter_f32<<<dim3((nnz4 + 255) / 256), dim3(256), 0, stream>>>(idx4, val4, nnz4, W4, 320);
    scatter_f32<<<dim3((nnz5 + 255) / 256), dim3(256), 0, stream>>>(idx5, val5, nnz5, W5, 256);

    // 4) layer 1: MFMA GEMM, split-K = 30 (chunk 4000 = 125*32)
    gemm1<<<dim3(20, 30), dim3(256), 0, stream>>>(Xb, W1, y1, 4000);

    // 5) BN1 + silu (b1 cancels inside BN)
    bn_silu<<<dim3(N1P), dim3(256), 0, stream>>>(y1, N1P, 600, g1, be1, h1);

    // 6) layer 2: silu(h1 @ W2^T + b2)
    small_gemm<1, 0><<<dim3(8, N2P / 64), dim3(256), 0, stream>>>(h1, N1P, W2, 640, b2, 600,
                                                                  h2, N2P, N2P, 640);
    // 7) layer 3 + BN2 + silu (b3 cancels)
    small_gemm<0, 0><<<dim3(8, N3P / 64), dim3(256), 0, stream>>>(h2, N2P, W3, 640, nullptr, 0,
                                                                  y3, N3P, N3P, 640);
    bn_silu<<<dim3(N3P), dim3(256), 0, stream>>>(y3, N3P, 300, g2, be2, h3);

    // 8) layer 4 + BN3 + silu (b4 cancels)
    small_gemm<0, 0><<<dim3(8, N4P / 64), dim3(256), 0, stream>>>(h3, N3P, W4, 320, nullptr, 0,
                                                                  y4, N4P, N4P, 320);
    bn_silu<<<dim3(N4P), dim3(256), 0, stream>>>(y4, N4P, 200, g3, be3, h4);

    // 9) layer 5: h4 @ W5^T + b5 -> d_out (fp32, compact 512x200)
    small_gemm<0, 1><<<dim3(8, N5P / 64), dim3(256), 0, stream>>>(h4, N4P, W5, 256, b5, 200,
                                                                  (float*)d_out, 200, 200, 256);
    (void)n_in; (void)out_size; (void)ws_size;
}